// Round 1
// baseline (448.260 us; speedup 1.0000x reference)
//
#include <hip/hip_runtime.h>

#define NN 16384
#define HH 32
#define GG 8
#define DD 128
#define RR 4
#define NGROUPS 4
#define NBAND 32

// out layout: index_q [N,4,128] | index_k [N,128] | weights [N,4]
// offsets (floats): 0 | N*512 | N*512 + N*128

__global__ __launch_bounds__(256) void idxer_kernel(
    const float* __restrict__ q, const float* __restrict__ k,
    const float* __restrict__ v, const float* __restrict__ proj,
    const float* __restrict__ vt, float* __restrict__ out)
{
    const int b = blockIdx.x;
    const int tid = threadIdx.x;

    __shared__ float sq[HH * DD];        // 4096 floats, 16 KB
    __shared__ float sk[GG * DD];        // 1024 floats
    __shared__ float sv[GG * DD];        // 1024 floats
    __shared__ float sproj[NBAND * 33];  // stride 33: avoids 32-way bank conflict
    __shared__ float sw[HH];             // per-head sum of squares

    // ---- stage to LDS (all coalesced) ----
    {
        const float4* q4 = (const float4*)(q + (size_t)b * (HH * DD));
        float4* s4 = (float4*)sq;
        #pragma unroll
        for (int i = 0; i < 4; ++i) s4[tid + 256 * i] = q4[tid + 256 * i];
        const float4* k4 = (const float4*)(k + (size_t)b * (GG * DD));
        ((float4*)sk)[tid] = k4[tid];
        const float4* v4 = (const float4*)(v + (size_t)b * (GG * DD));
        ((float4*)sv)[tid] = v4[tid];
        #pragma unroll
        for (int i = 0; i < 4; ++i) {
            int p = tid + 256 * i;                    // p = n*32 + (j*2+r)
            sproj[(p >> 5) * 33 + (p & 31)] = proj[p];
        }
    }
    __syncthreads();

    // ---- index_q: thread -> (group, im, n); computes r=0 and r=1 ----
    // fold inverse: d = ((n&15)*2 + (j>>3))*2 + (n>>4) + im*64, head = (j&7)*4 + group
    {
        const int group = tid >> 6;
        const int im = (tid >> 5) & 1;
        const int n = tid & 31;
        const int dbase = (n & 15) * 4 + (n >> 4) + im * 64;
        float acc0 = 0.f, acc1 = 0.f;
        #pragma unroll
        for (int j = 0; j < 16; ++j) {
            const int d = dbase + (j >> 3) * 2;
            const int head = (j & 7) * 4 + group;
            const float qv = sq[head * DD + d];
            acc0 += qv * sproj[n * 33 + j * 2];
            acc1 += qv * sproj[n * 33 + j * 2 + 1];
        }
        float2* o2 = (float2*)out;
        o2[(size_t)b * 256 + group * 64 + im * 32 + n] = make_float2(acc0, acc1);
    }

    // ---- index_k: threads 0..63 -> (im, n) ----
    if (tid < 64) {
        const int im = tid >> 5;
        const int n = tid & 31;
        const int dbase = (n & 15) * 4 + (n >> 4) + im * 64;
        float acc0 = 0.f, acc1 = 0.f;
        #pragma unroll
        for (int j = 0; j < 16; ++j) {
            const int d = dbase + (j >> 3) * 2;
            const int g = j & 7;
            const float kv = sk[g * DD + d];
            acc0 += kv * sproj[n * 33 + j * 2];
            acc1 += kv * sproj[n * 33 + j * 2 + 1];
        }
        float2* o2 = (float2*)(out + (size_t)NN * 512);
        o2[(size_t)b * 64 + im * 32 + n] = make_float2(acc0, acc1);
    }

    // ---- weights: thread = h*8 + s; vt[h][d][0..3] as float4 ----
    {
        const int h = tid >> 3;
        const int s = tid & 7;
        const int g = h >> 2;
        const float4* vt4 = (const float4*)vt;   // [H][D] float4 over R
        float a0 = 0.f, a1 = 0.f, a2 = 0.f, a3 = 0.f;
        #pragma unroll
        for (int i = 0; i < 16; ++i) {
            const int d = i * 8 + s;
            const float4 w4 = vt4[h * DD + d];
            const float vv = sv[g * DD + d];
            a0 += vv * w4.x; a1 += vv * w4.y; a2 += vv * w4.z; a3 += vv * w4.w;
        }
        #pragma unroll
        for (int off = 4; off >= 1; off >>= 1) {
            a0 += __shfl_down(a0, off, 8);
            a1 += __shfl_down(a1, off, 8);
            a2 += __shfl_down(a2, off, 8);
            a3 += __shfl_down(a3, off, 8);
        }
        if (s == 0) sw[h] = a0 * a0 + a1 * a1 + a2 * a2 + a3 * a3;
    }
    __syncthreads();

    if (tid < NGROUPS) {
        float acc = 0.f;
        #pragma unroll
        for (int g = 0; g < 8; ++g) acc += sw[g * 4 + tid];
        out[(size_t)NN * 512 + (size_t)NN * 128 + (size_t)b * 4 + tid] = sqrtf(acc);
    }
}

extern "C" void kernel_launch(void* const* d_in, const int* in_sizes, int n_in,
                              void* d_out, int out_size, void* d_ws, size_t ws_size,
                              hipStream_t stream) {
    const float* q    = (const float*)d_in[0];
    const float* k    = (const float*)d_in[1];
    const float* v    = (const float*)d_in[2];
    const float* proj = (const float*)d_in[3];
    const float* vt   = (const float*)d_in[4];
    float* out = (float*)d_out;
    idxer_kernel<<<NN, 256, 0, stream>>>(q, k, v, proj, vt, out);
}